// Round 11
// baseline (261.432 us; speedup 1.0000x reference)
//
#include <hip/hip_runtime.h>
#include <math.h>

// Router: x[8192,4096] fp32; Wg,Wc[64,4096]; scores=|cls*silu(gate)|, softmax,
// top-8 of scores+bias, weights = 1 + scores*extra_scale (gathered).
// Out: weights [8192,8] fp32, then indices [8192,8] written as float values.
//
// v10: math/bits identical to v5..v9 (3-way bf16 split, 6-product order, same
// per-acc k-order -> P bit-identical -> absmax 0). Pipeline fix from v9b's
// flat result (occupancy 2x brought nothing -> per-step LATENCY was binding):
//  - REGISTER double-buffer of ALL VMEM: B(t+1) + x(t+2) issued BEFORE the
//    MFMAs of step t into a second named register set (static names, swap via
//    unrolled 2-step loop). Steady-state waits are for loads issued a full
//    step earlier -> zero exposed L2/HBM latency.
//  - __launch_bounds__(512,4): VGPR<=128 (~100 used, no spill risk).
//  - T5 setprio(1) around the MFMA cluster.

#define T_DIM 8192
#define D_DIM 4096
#define E_DIM 64
#define N2    128      // 64 gate cols + 64 cls cols
#define KTOP  8
#define MB_ROWS 64     // rows per workgroup (2 row-groups of 32)

// LDS fragment layout strides (ushorts): [bf][rg][p][h2][le][j]
#define LDS_H2S 512
#define LDS_PS  1040   // 1024 + 16 pad -> parts shifted 8 banks
#define LDS_RGS (3 * LDS_PS)
#define LDS_BFS (2 * LDS_RGS)

typedef __attribute__((ext_vector_type(8)))  short bfrag8;   // 8 bf16 (4 VGPRs)
typedef __attribute__((ext_vector_type(16))) float f32x16;   // 32x32 C/D frag
typedef __attribute__((ext_vector_type(4)))  float f4;       // clang vec (nt ok)

__device__ __forceinline__ unsigned short f2bf_rne(float f) {
    unsigned int u = __float_as_uint(f);
    unsigned int r = u + 0x7fffu + ((u >> 16) & 1u);        // round-nearest-even
    return (unsigned short)(r >> 16);
}
__device__ __forceinline__ float bf2f(unsigned short h) {
    return __uint_as_float(((unsigned int)h) << 16);
}
// v = bf2f(h) + bf2f(m) + bf2f(l) + eps, |eps| <= 2^-27 |v|
__device__ __forceinline__ void split3(float v, unsigned short& h,
                                       unsigned short& m, unsigned short& l) {
    h = f2bf_rne(v);
    const float r1 = v - bf2f(h);          // exact in fp32
    m = f2bf_rne(r1);
    const float r2 = r1 - bf2f(m);         // exact in fp32
    l = f2bf_rne(r2);
}

// ---------------- Kernel 0: W -> packed fragment-major bf16 hi/mid/lo ----------
// Wpk element index: ((((k32*4 + n)*3 + p)*2 + h2)*64 + lane)*8 + j
//   holds part-p of W[col = n*32 + (lane&31)][k32*32 + h2*16 + (lane>>5)*8 + j]
// => a wave's B fragment load is 64 lanes x 16B CONTIGUOUS (1 KB). Total 3 MB.
__global__ __launch_bounds__(256)
void router_prep(const float* __restrict__ Wg, const float* __restrict__ Wc,
                 unsigned short* __restrict__ Wpk)
{
    const int t   = blockIdx.x * 256 + threadIdx.x;  // 65536 threads
    const int col = t >> 9;                          // 0..127
    const int ch  = t & 511;                         // 8-float chunk within row
    const int k   = ch << 3;

    const float* src = (col < E_DIM) ? (Wg + (size_t)col * D_DIM)
                                     : (Wc + (size_t)(col - E_DIM) * D_DIM);
    const float4 w0 = ((const float4*)(src + k))[0];
    const float4 w1 = ((const float4*)(src + k))[1];
    const float v[8] = {w0.x, w0.y, w0.z, w0.w, w1.x, w1.y, w1.z, w1.w};

    unsigned short hv[8], mv[8], lv[8];
    #pragma unroll
    for (int j = 0; j < 8; ++j) split3(v[j], hv[j], mv[j], lv[j]);

    const int k32 = k >> 5, h2 = (k >> 4) & 1, lh = (k >> 3) & 1;
    const int n = col >> 5, lane = lh * 32 + (col & 31);
    const size_t base = ((((size_t)k32 * 4 + n) * 3 + 0) * 2 + h2) * 512 + (size_t)lane * 8;
    // p stride = 2*512 = 1024 elements
    *(ushort4*)(Wpk + base)          = make_ushort4(hv[0], hv[1], hv[2], hv[3]);
    *(ushort4*)(Wpk + base + 4)      = make_ushort4(hv[4], hv[5], hv[6], hv[7]);
    *(ushort4*)(Wpk + base + 1024)   = make_ushort4(mv[0], mv[1], mv[2], mv[3]);
    *(ushort4*)(Wpk + base + 1028)   = make_ushort4(mv[4], mv[5], mv[6], mv[7]);
    *(ushort4*)(Wpk + base + 2048)   = make_ushort4(lv[0], lv[1], lv[2], lv[3]);
    *(ushort4*)(Wpk + base + 2052)   = make_ushort4(lv[4], lv[5], lv[6], lv[7]);
}

// ---------------- Kernel 1: 3-way-split MFMA GEMM, partials P[ks][T][128] ------
// Block: 512 thr = 8 waves (rg = wid>>2 row-group, wc = wid&3 col-quarter).
// Wave tile 32x32. Steady-state per step: issue B(t+1)+x(t+2) -> MFMA(t) with
// register-resident B(t) -> ds_write x(t+1) -> barrier. No exposed VMEM waits.
__global__ __launch_bounds__(512, 4)
void router_gemm(const float* __restrict__ x,
                 const unsigned short* __restrict__ Wpk,
                 float* __restrict__ P,
                 int sliceK)
{
    __shared__ unsigned short sF[2 * LDS_BFS];       // ~25 KB

    const int tid  = threadIdx.x;
    const int lane = tid & 63;
    const int wid  = tid >> 6;
    const int rg   = wid >> 2;           // row-group (0/1)
    const int wc   = wid & 3;            // col-quarter (B n-tile)
    const int l31  = lane & 31;
    const int lh   = lane >> 5;
    const int mb   = blockIdx.x;
    const int ks   = blockIdx.y;
    const int k0   = ks * sliceK;
    const int NT   = sliceK >> 5;        // 32-k steps (always even)
    const int brow0 = mb * MB_ROWS;

    // staging map: thread -> (srow 0..63, kq 0..7); one f4 per tile
    const int srow = tid >> 3;
    const int kq   = tid & 7;
    const int rgs  = srow >> 5;          // staging row-group
    const int h2w  = kq >> 2;
    const int lew  = ((kq >> 1) & 1) * 32 + (srow & 31);
    const int jw   = (kq & 1) * 4;
    const int wbase = rgs * LDS_RGS + h2w * LDS_H2S + lew * 8 + jw;
    const float* gsrc = x + (size_t)(brow0 + srow) * D_DIM + k0 + kq * 4;

    f32x16 acc;
    #pragma unroll
    for (int r = 0; r < 16; ++r) acc[r] = 0.f;

    // split one f4 into LDS at buffer bf_ (same values/addresses as v8/v9)
    #define WRITE_ONE(v_, bf_)                                                   \
        {                                                                        \
            ushort4 hv_, mv_, lv_;                                               \
            unsigned short h_, m_, l_;                                           \
            split3((v_).x, h_, m_, l_); hv_.x = h_; mv_.x = m_; lv_.x = l_;      \
            split3((v_).y, h_, m_, l_); hv_.y = h_; mv_.y = m_; lv_.y = l_;      \
            split3((v_).z, h_, m_, l_); hv_.z = h_; mv_.z = m_; lv_.z = l_;      \
            split3((v_).w, h_, m_, l_); hv_.w = h_; mv_.w = m_; lv_.w = l_;      \
            const int o_ = (bf_) * LDS_BFS + wbase;                              \
            *(ushort4*)&sF[o_]              = hv_;                               \
            *(ushort4*)&sF[o_ + LDS_PS]     = mv_;                               \
            *(ushort4*)&sF[o_ + 2 * LDS_PS] = lv_;                               \
        }

    // load one k32-step's 6 B fragments into named regs (wave-contiguous, L2)
    #define LOAD_B(P_, k32_)                                                     \
        {                                                                        \
            const unsigned short* bb0_ =                                         \
                Wpk + (((((size_t)(k32_)) * 4 + wc) * 3) * 2 * 64 + (size_t)lane) * 8; \
            P_##h0 = *(const bfrag8*)(bb0_);                                     \
            P_##m0 = *(const bfrag8*)(bb0_ + 1024);                              \
            P_##l0 = *(const bfrag8*)(bb0_ + 2048);                              \
            P_##h1 = *(const bfrag8*)(bb0_ + 512);                               \
            P_##m1 = *(const bfrag8*)(bb0_ + 1536);                              \
            P_##l1 = *(const bfrag8*)(bb0_ + 2560);                              \
        }

    // 12 MFMAs for step in buffer bf_ with B set P_ (order == v5..v9 exactly)
    #define MFMA_STEP(bf_, P_)                                                   \
        {                                                                        \
            const int fb_ = (bf_) * LDS_BFS + rg * LDS_RGS;                      \
            __builtin_amdgcn_s_setprio(1);                                       \
            {                                                                    \
                const int ab = fb_ + lane * 8;                                   \
                const bfrag8 ah = *(const bfrag8*)&sF[ab];                       \
                const bfrag8 am = *(const bfrag8*)&sF[ab + LDS_PS];              \
                const bfrag8 al = *(const bfrag8*)&sF[ab + 2 * LDS_PS];          \
                acc = __builtin_amdgcn_mfma_f32_32x32x16_bf16(ah, P_##l0, acc, 0, 0, 0); \
                acc = __builtin_amdgcn_mfma_f32_32x32x16_bf16(al, P_##h0, acc, 0, 0, 0); \
                acc = __builtin_amdgcn_mfma_f32_32x32x16_bf16(am, P_##m0, acc, 0, 0, 0); \
                acc = __builtin_amdgcn_mfma_f32_32x32x16_bf16(ah, P_##m0, acc, 0, 0, 0); \
                acc = __builtin_amdgcn_mfma_f32_32x32x16_bf16(am, P_##h0, acc, 0, 0, 0); \
                acc = __builtin_amdgcn_mfma_f32_32x32x16_bf16(ah, P_##h0, acc, 0, 0, 0); \
            }                                                                    \
            {                                                                    \
                const int ab = fb_ + LDS_H2S + lane * 8;                         \
                const bfrag8 ah = *(const bfrag8*)&sF[ab];                       \
                const bfrag8 am = *(const bfrag8*)&sF[ab + LDS_PS];              \
                const bfrag8 al = *(const bfrag8*)&sF[ab + 2 * LDS_PS];          \
                acc = __builtin_amdgcn_mfma_f32_32x32x16_bf16(ah, P_##l1, acc, 0, 0, 0); \
                acc = __builtin_amdgcn_mfma_f32_32x32x16_bf16(al, P_##h1, acc, 0, 0, 0); \
                acc = __builtin_amdgcn_mfma_f32_32x32x16_bf16(am, P_##m1, acc, 0, 0, 0); \
                acc = __builtin_amdgcn_mfma_f32_32x32x16_bf16(ah, P_##m1, acc, 0, 0, 0); \
                acc = __builtin_amdgcn_mfma_f32_32x32x16_bf16(am, P_##h1, acc, 0, 0, 0); \
                acc = __builtin_amdgcn_mfma_f32_32x32x16_bf16(ah, P_##h1, acc, 0, 0, 0); \
            }                                                                    \
            __builtin_amdgcn_s_setprio(0);                                       \
        }

    // named B register double-buffer (static names only, rule #20)
    bfrag8 Ah0, Am0, Al0, Ah1, Am1, Al1;     // set A
    bfrag8 Bh0, Bm0, Bl0, Bh1, Bm1, Bl1;     // set B

    // prologue: stage tile 0; load B(0) into set A; load x(1) into xa
    {
        const f4 v0 = __builtin_nontemporal_load((const f4*)gsrc);
        WRITE_ONE(v0, 0);
    }
    LOAD_B(A, (k0 >> 5));
    const int t1c = (1 < NT) ? 1 : 0;
    f4 xa = __builtin_nontemporal_load((const f4*)(gsrc + t1c * 32));
    f4 xb;
    asm volatile("s_waitcnt lgkmcnt(0)" ::: "memory");
    __builtin_amdgcn_s_barrier();

    for (int t = 0; t < NT; t += 2) {
        // ===== even step t: consume (buf0, set A); prefetch B(t+1)->B, x(t+2)
        {
            const int tb = (t + 1 < NT) ? t + 1 : t;          // clamped (redundant ok)
            LOAD_B(B, ((k0 + tb * 32) >> 5));
            const int tx = (t + 2 < NT) ? t + 2 : NT - 1;
            xb = __builtin_nontemporal_load((const f4*)(gsrc + tx * 32));

            MFMA_STEP(0, A);

            if (t + 1 < NT) WRITE_ONE(xa, 1);
            asm volatile("s_waitcnt lgkmcnt(0)" ::: "memory");
            __builtin_amdgcn_s_barrier();
        }
        // ===== odd step t+1: consume (buf1, set B); prefetch B(t+2)->A, x(t+3)
        {
            const int tb = (t + 2 < NT) ? t + 2 : t + 1;
            LOAD_B(A, ((k0 + tb * 32) >> 5));
            const int tx = (t + 3 < NT) ? t + 3 : NT - 1;
            xa = __builtin_nontemporal_load((const f4*)(gsrc + tx * 32));

            MFMA_STEP(1, B);

            if (t + 2 < NT) WRITE_ONE(xb, 0);
            asm volatile("s_waitcnt lgkmcnt(0)" ::: "memory");
            __builtin_amdgcn_s_barrier();
        }
    }
    #undef WRITE_ONE
    #undef LOAD_B
    #undef MFMA_STEP

    // store partial C tile: P[ks][row][col], non-temporal (read once by topk)
    // C/D (m74/m101): col = lane&31, row = (r&3) + 8*(r>>2) + 4*(lane>>5)
    float* Pb = P + ((size_t)ks * T_DIM + brow0 + rg * 32) * N2 + wc * 32 + l31;
    #pragma unroll
    for (int r = 0; r < 16; ++r) {
        const int wrow = (r & 3) + 8 * (r >> 2) + 4 * lh;
        __builtin_nontemporal_store(acc[r], &Pb[(size_t)wrow * N2]);
    }
}

// ---------------- Kernel 2: reduce slices + silu/abs/softmax + biased top-8 ----
// (unchanged from the passing kernel — exact index ordering proven)
__global__ __launch_bounds__(256)
void router_topk(const float* __restrict__ P,
                 const float* __restrict__ scale,
                 const float* __restrict__ bias,
                 float* __restrict__ out,
                 int ksplit)
{
    const int lane = threadIdx.x & 63;   // expert id
    const int wid  = threadIdx.x >> 6;
    const int row  = blockIdx.x * 4 + wid;

    float g = 0.f, c = 0.f;
    for (int ks = 0; ks < ksplit; ++ks) {
        const float* p = P + ((size_t)ks * T_DIM + row) * N2;
        g += p[lane];
        c += p[E_DIM + lane];
    }
    const float sg = g / (1.f + expf(-g));   // silu(gate)
    const float v  = fabsf(c * sg);          // score pre-softmax

    // fp32 softmax across the 64 lanes
    float m = v;
    #pragma unroll
    for (int off = 32; off >= 1; off >>= 1) m = fmaxf(m, __shfl_xor(m, off));
    const float e = expf(v - m);
    float Z = e;
    #pragma unroll
    for (int off = 32; off >= 1; off >>= 1) Z += __shfl_xor(Z, off);
    const float s = e / Z;

    const float sc  = scale[lane];
    float cur = s + bias[lane];              // selection key

    float myw = 0.f; int myi = 0;
    #pragma unroll
    for (int j = 0; j < KTOP; ++j) {
        // wave argmax, ties -> lowest index (matches jax.lax.top_k)
        float bv = cur; int bi = lane;
        #pragma unroll
        for (int off = 32; off >= 1; off >>= 1) {
            const float ov = __shfl_xor(bv, off);
            const int   oi = __shfl_xor(bi, off);
            if (ov > bv || (ov == bv && oi < bi)) { bv = ov; bi = oi; }
        }
        const float s_bi  = __shfl(s,  bi);
        const float sc_bi = __shfl(sc, bi);
        const float w = 1.f + s_bi * sc_bi;  // "original" gathered at bi
        if (lane == j)  { myw = w; myi = bi; }
        if (lane == bi) cur = -INFINITY;
    }

    if (lane < KTOP) {
        out[(size_t)row * KTOP + lane] = myw;
        out[(size_t)T_DIM * KTOP + (size_t)row * KTOP + lane] = (float)myi;
    }
}

extern "C" void kernel_launch(void* const* d_in, const int* in_sizes, int n_in,
                              void* d_out, int out_size, void* d_ws, size_t ws_size,
                              hipStream_t stream)
{
    const float* x  = (const float*)d_in[0];
    const float* Wg = (const float*)d_in[1];
    const float* Wc = (const float*)d_in[2];
    const float* sc = (const float*)d_in[3];
    const float* bs = (const float*)d_in[4];
    float* out = (float*)d_out;
    float* P   = (float*)d_ws;

    const size_t PER = (size_t)T_DIM * N2 * sizeof(float);           // 4 MB per slice
    const size_t WSP = (size_t)N2 * D_DIM * sizeof(unsigned short);  // 1 MB per W part

    // Need S*4MB (partials) + 3MB (packed W); degrade gracefully if ws is small.
    int S = 8;
    while (S > 1 && (size_t)S * PER + 3 * WSP > ws_size) S >>= 1;
    const int sliceK = D_DIM / S;

    unsigned short* Wpk = (unsigned short*)((char*)d_ws + (size_t)S * PER);

    router_prep<<<256, 256, 0, stream>>>(Wg, Wc, Wpk);
    router_gemm<<<dim3(T_DIM / MB_ROWS, S), 512, 0, stream>>>(x, Wpk, P, sliceK);
    router_topk<<<T_DIM / 4, 256, 0, stream>>>(P, sc, bs, out, S);
}

// Round 12
// 257.109 us; speedup vs baseline: 1.0168x; 1.0168x over previous
//
#include <hip/hip_runtime.h>
#include <math.h>

// Router: x[8192,4096] fp32; Wg,Wc[64,4096]; scores=|cls*silu(gate)|, softmax,
// top-8 of scores+bias, weights = 1 + scores*extra_scale (gathered).
// Out: weights [8192,8] fp32, then indices [8192,8] written as float values.
//
// v11: math/bits identical to v3..v10 (3-way bf16 split, 6-product order, same
// per-acc k-order, S=8 slices -> P bit-identical -> absmax 0). Structural fix
// from the v7-v10 ledger: B fragments were re-fetched per 32-row tile (6KB B
// per 768 cyc of MFMA) -> B-BW + barrier bubbles dominated. Now:
//  - wave tile 128 rows x 32 cols (acc[4]): 48 MFMA (1536 cyc) per 6KB B-step,
//    B traffic 768->192 MB. Block 256thr/4 waves (wave = col-quarter), grid
//    (64,8), 2 blocks/CU interleaving across barriers.
//  - B loads first, x-prefetch last (in-order vmcnt, m135); depth-1.
//  - LDS dbuf 49.5KB, H2S=520/PS=1056 pads kill the 4-way ds_write conflict;
//    staging thread = 16 floats (1 row-half), 6x ds_write_b128.

#define T_DIM 8192
#define D_DIM 4096
#define E_DIM 64
#define N2    128      // 64 gate cols + 64 cls cols
#define KTOP  8
#define MB_ROWS 128    // rows per workgroup (4 row-groups of 32, all per wave)

// LDS fragment layout strides (ushorts): [bf][rg][p][h2][le][j]
#define LDS_H2S 520    // 512 + 8 pad  (+4 banks per h2)
#define LDS_PS  1056   // 2*520 + 16   (+8 banks per part)
#define LDS_RGS (3 * LDS_PS)
#define LDS_BFS (4 * LDS_RGS)

typedef __attribute__((ext_vector_type(8)))  short bfrag8;   // 8 bf16 (4 VGPRs)
typedef __attribute__((ext_vector_type(8)))  unsigned short us8;
typedef __attribute__((ext_vector_type(16))) float f32x16;   // 32x32 C/D frag
typedef __attribute__((ext_vector_type(4)))  float f4;       // clang vec (nt ok)

__device__ __forceinline__ unsigned short f2bf_rne(float f) {
    unsigned int u = __float_as_uint(f);
    unsigned int r = u + 0x7fffu + ((u >> 16) & 1u);        // round-nearest-even
    return (unsigned short)(r >> 16);
}
__device__ __forceinline__ float bf2f(unsigned short h) {
    return __uint_as_float(((unsigned int)h) << 16);
}
// v = bf2f(h) + bf2f(m) + bf2f(l) + eps, |eps| <= 2^-27 |v|
__device__ __forceinline__ void split3(float v, unsigned short& h,
                                       unsigned short& m, unsigned short& l) {
    h = f2bf_rne(v);
    const float r1 = v - bf2f(h);          // exact in fp32
    m = f2bf_rne(r1);
    const float r2 = r1 - bf2f(m);         // exact in fp32
    l = f2bf_rne(r2);
}

// ---------------- Kernel 0: W -> packed fragment-major bf16 hi/mid/lo ----------
// Wpk element index: ((((k32*4 + n)*3 + p)*2 + h2)*64 + lane)*8 + j
//   holds part-p of W[col = n*32 + (lane&31)][k32*32 + h2*16 + (lane>>5)*8 + j]
// => a wave's B fragment load is 64 lanes x 16B CONTIGUOUS (1 KB). Total 3 MB.
__global__ __launch_bounds__(256)
void router_prep(const float* __restrict__ Wg, const float* __restrict__ Wc,
                 unsigned short* __restrict__ Wpk)
{
    const int t   = blockIdx.x * 256 + threadIdx.x;  // 65536 threads
    const int col = t >> 9;                          // 0..127
    const int ch  = t & 511;                         // 8-float chunk within row
    const int k   = ch << 3;

    const float* src = (col < E_DIM) ? (Wg + (size_t)col * D_DIM)
                                     : (Wc + (size_t)(col - E_DIM) * D_DIM);
    const float4 w0 = ((const float4*)(src + k))[0];
    const float4 w1 = ((const float4*)(src + k))[1];
    const float v[8] = {w0.x, w0.y, w0.z, w0.w, w1.x, w1.y, w1.z, w1.w};

    unsigned short hv[8], mv[8], lv[8];
    #pragma unroll
    for (int j = 0; j < 8; ++j) split3(v[j], hv[j], mv[j], lv[j]);

    const int k32 = k >> 5, h2 = (k >> 4) & 1, lh = (k >> 3) & 1;
    const int n = col >> 5, lane = lh * 32 + (col & 31);
    const size_t base = ((((size_t)k32 * 4 + n) * 3 + 0) * 2 + h2) * 512 + (size_t)lane * 8;
    // p stride = 2*512 = 1024 elements
    *(ushort4*)(Wpk + base)          = make_ushort4(hv[0], hv[1], hv[2], hv[3]);
    *(ushort4*)(Wpk + base + 4)      = make_ushort4(hv[4], hv[5], hv[6], hv[7]);
    *(ushort4*)(Wpk + base + 1024)   = make_ushort4(mv[0], mv[1], mv[2], mv[3]);
    *(ushort4*)(Wpk + base + 1028)   = make_ushort4(mv[4], mv[5], mv[6], mv[7]);
    *(ushort4*)(Wpk + base + 2048)   = make_ushort4(lv[0], lv[1], lv[2], lv[3]);
    *(ushort4*)(Wpk + base + 2052)   = make_ushort4(lv[4], lv[5], lv[6], lv[7]);
}

// ---------------- Kernel 1: 3-way-split MFMA GEMM, partials P[ks][T][128] ------
// Block: 256 thr = 4 waves; wave wc owns cols wc*32..wc*32+31 and ALL 128 rows
// (four 32-row groups -> acc[4]; 48 MFMA per k32-step from one 6KB B fetch).
// Staging thread (srow=tid>>1, seg=tid&1): 16 floats of row srow (one h2),
// 4x nt f4 global loads, split3 once, 6x ds_write_b128 fragment layout.
__global__ __launch_bounds__(256, 2)
void router_gemm(const float* __restrict__ x,
                 const unsigned short* __restrict__ Wpk,
                 float* __restrict__ P,
                 int sliceK)
{
    __shared__ unsigned short sF[2 * LDS_BFS];       // ~49.5 KB

    const int tid  = threadIdx.x;
    const int lane = tid & 63;
    const int wc   = tid >> 6;           // wave = col-quarter (B n-tile)
    const int l31  = lane & 31;
    const int lh   = lane >> 5;
    const int mb   = blockIdx.x;
    const int ks   = blockIdx.y;
    const int k0   = ks * sliceK;
    const int NT   = sliceK >> 5;        // 32-k steps
    const int brow0 = mb * MB_ROWS;

    // staging map: thread -> (srow 0..127, seg = staged h2)
    const int srow = tid >> 1;
    const int seg  = tid & 1;
    const int wbase = (srow >> 5) * LDS_RGS + seg * LDS_H2S + (srow & 31) * 8;
    const float* gsrc = x + (size_t)(brow0 + srow) * D_DIM + k0 + seg * 16;

    f32x16 acc[4];
    #pragma unroll
    for (int rg = 0; rg < 4; ++rg)
        #pragma unroll
        for (int r = 0; r < 16; ++r) acc[rg][r] = 0.f;

    // split 16 staged floats into LDS buffer bf_: per lh j-group, 3 parts
    #define WRITE_TILE(bf_)                                                      \
        {                                                                        \
            const float fv[16] = {c0.x,c0.y,c0.z,c0.w, c1.x,c1.y,c1.z,c1.w,      \
                                  c2.x,c2.y,c2.z,c2.w, c3.x,c3.y,c3.z,c3.w};     \
            _Pragma("unroll")                                                    \
            for (int lh_ = 0; lh_ < 2; ++lh_) {                                  \
                us8 hv_, mv_, lv_;                                               \
                _Pragma("unroll")                                                \
                for (int j_ = 0; j_ < 8; ++j_) {                                 \
                    unsigned short h_, m_, l_;                                   \
                    split3(fv[lh_ * 8 + j_], h_, m_, l_);                        \
                    hv_[j_] = h_; mv_[j_] = m_; lv_[j_] = l_;                    \
                }                                                                \
                const int o_ = (bf_) * LDS_BFS + wbase + lh_ * 256;              \
                *(us8*)&sF[o_]              = hv_;                               \
                *(us8*)&sF[o_ + LDS_PS]     = mv_;                               \
                *(us8*)&sF[o_ + 2 * LDS_PS] = lv_;                               \
            }                                                                    \
        }

    f4 c0, c1, c2, c3;
    // prologue: stage tile 0
    c0 = __builtin_nontemporal_load((const f4*)(gsrc));
    c1 = __builtin_nontemporal_load((const f4*)(gsrc + 4));
    c2 = __builtin_nontemporal_load((const f4*)(gsrc + 8));
    c3 = __builtin_nontemporal_load((const f4*)(gsrc + 12));
    WRITE_TILE(0);
    asm volatile("s_waitcnt lgkmcnt(0)" ::: "memory");
    __builtin_amdgcn_s_barrier();

    for (int t = 0; t < NT; ++t) {
        const int bf = t & 1;
        const size_t k32 = (size_t)((k0 + t * 32) >> 5);
        const bool more = (t + 1 < NT);

        // ---- B loads FIRST (L2-hot, shared by all 4 row-groups)
        const unsigned short* bb =
            Wpk + (((k32 * 4 + wc) * 3) * 2 * 64 + (size_t)lane) * 8;
        const bfrag8 bh0 = *(const bfrag8*)(bb);
        const bfrag8 bm0 = *(const bfrag8*)(bb + 1024);
        const bfrag8 bl0 = *(const bfrag8*)(bb + 2048);
        const bfrag8 bh1 = *(const bfrag8*)(bb + 512);
        const bfrag8 bm1 = *(const bfrag8*)(bb + 1536);
        const bfrag8 bl1 = *(const bfrag8*)(bb + 2560);

        // ---- x prefetch LAST (youngest; B-wait never drains it -- m135)
        if (more) {
            const float* gp = gsrc + (t + 1) * 32;
            c0 = __builtin_nontemporal_load((const f4*)(gp));
            c1 = __builtin_nontemporal_load((const f4*)(gp + 4));
            c2 = __builtin_nontemporal_load((const f4*)(gp + 8));
            c3 = __builtin_nontemporal_load((const f4*)(gp + 12));
        }

        // ---- 4 row-groups x (6 ds_read + 12 MFMA); per-acc order == v3..v10
        __builtin_amdgcn_s_setprio(1);
        #pragma unroll
        for (int rg = 0; rg < 4; ++rg) {
            const int ab = bf * LDS_BFS + rg * LDS_RGS + lane * 8;
            const bfrag8 ah0 = *(const bfrag8*)&sF[ab];
            const bfrag8 am0 = *(const bfrag8*)&sF[ab + LDS_PS];
            const bfrag8 al0 = *(const bfrag8*)&sF[ab + 2 * LDS_PS];
            const bfrag8 ah1 = *(const bfrag8*)&sF[ab + LDS_H2S];
            const bfrag8 am1 = *(const bfrag8*)&sF[ab + LDS_H2S + LDS_PS];
            const bfrag8 al1 = *(const bfrag8*)&sF[ab + LDS_H2S + 2 * LDS_PS];
            // h2 = 0, smallest products first (bit-identical chain)
            acc[rg] = __builtin_amdgcn_mfma_f32_32x32x16_bf16(ah0, bl0, acc[rg], 0, 0, 0);
            acc[rg] = __builtin_amdgcn_mfma_f32_32x32x16_bf16(al0, bh0, acc[rg], 0, 0, 0);
            acc[rg] = __builtin_amdgcn_mfma_f32_32x32x16_bf16(am0, bm0, acc[rg], 0, 0, 0);
            acc[rg] = __builtin_amdgcn_mfma_f32_32x32x16_bf16(ah0, bm0, acc[rg], 0, 0, 0);
            acc[rg] = __builtin_amdgcn_mfma_f32_32x32x16_bf16(am0, bh0, acc[rg], 0, 0, 0);
            acc[rg] = __builtin_amdgcn_mfma_f32_32x32x16_bf16(ah0, bh0, acc[rg], 0, 0, 0);
            // h2 = 1
            acc[rg] = __builtin_amdgcn_mfma_f32_32x32x16_bf16(ah1, bl1, acc[rg], 0, 0, 0);
            acc[rg] = __builtin_amdgcn_mfma_f32_32x32x16_bf16(al1, bh1, acc[rg], 0, 0, 0);
            acc[rg] = __builtin_amdgcn_mfma_f32_32x32x16_bf16(am1, bm1, acc[rg], 0, 0, 0);
            acc[rg] = __builtin_amdgcn_mfma_f32_32x32x16_bf16(ah1, bm1, acc[rg], 0, 0, 0);
            acc[rg] = __builtin_amdgcn_mfma_f32_32x32x16_bf16(am1, bh1, acc[rg], 0, 0, 0);
            acc[rg] = __builtin_amdgcn_mfma_f32_32x32x16_bf16(ah1, bh1, acc[rg], 0, 0, 0);
        }
        __builtin_amdgcn_s_setprio(0);

        // ---- write tile t+1 (vmcnt wait for c0..c3 covered by MFMA segment)
        if (more) WRITE_TILE(bf ^ 1);
        asm volatile("s_waitcnt lgkmcnt(0)" ::: "memory");
        __builtin_amdgcn_s_barrier();
    }
    #undef WRITE_TILE

    // store partial C tile: P[ks][row][col], non-temporal (read once by topk)
    // C/D (m74/m101): col = lane&31, row = (r&3) + 8*(r>>2) + 4*(lane>>5)
    #pragma unroll
    for (int rg = 0; rg < 4; ++rg) {
        float* Pb = P + ((size_t)ks * T_DIM + brow0 + rg * 32) * N2 + wc * 32 + l31;
        #pragma unroll
        for (int r = 0; r < 16; ++r) {
            const int wrow = (r & 3) + 8 * (r >> 2) + 4 * lh;
            __builtin_nontemporal_store(acc[rg][r], &Pb[(size_t)wrow * N2]);
        }
    }
}

// ---------------- Kernel 2: reduce slices + silu/abs/softmax + biased top-8 ----
// (unchanged from the passing kernel — exact index ordering proven)
__global__ __launch_bounds__(256)
void router_topk(const float* __restrict__ P,
                 const float* __restrict__ scale,
                 const float* __restrict__ bias,
                 float* __restrict__ out,
                 int ksplit)
{
    const int lane = threadIdx.x & 63;   // expert id
    const int wid  = threadIdx.x >> 6;
    const int row  = blockIdx.x * 4 + wid;

    float g = 0.f, c = 0.f;
    for (int ks = 0; ks < ksplit; ++ks) {
        const float* p = P + ((size_t)ks * T_DIM + row) * N2;
        g += p[lane];
        c += p[E_DIM + lane];
    }
    const float sg = g / (1.f + expf(-g));   // silu(gate)
    const float v  = fabsf(c * sg);          // score pre-softmax

    // fp32 softmax across the 64 lanes
    float m = v;
    #pragma unroll
    for (int off = 32; off >= 1; off >>= 1) m = fmaxf(m, __shfl_xor(m, off));
    const float e = expf(v - m);
    float Z = e;
    #pragma unroll
    for (int off = 32; off >= 1; off >>= 1) Z += __shfl_xor(Z, off);
    const float s = e / Z;

    const float sc  = scale[lane];
    float cur = s + bias[lane];              // selection key

    float myw = 0.f; int myi = 0;
    #pragma unroll
    for (int j = 0; j < KTOP; ++j) {
        // wave argmax, ties -> lowest index (matches jax.lax.top_k)
        float bv = cur; int bi = lane;
        #pragma unroll
        for (int off = 32; off >= 1; off >>= 1) {
            const float ov = __shfl_xor(bv, off);
            const int   oi = __shfl_xor(bi, off);
            if (ov > bv || (ov == bv && oi < bi)) { bv = ov; bi = oi; }
        }
        const float s_bi  = __shfl(s,  bi);
        const float sc_bi = __shfl(sc, bi);
        const float w = 1.f + s_bi * sc_bi;  // "original" gathered at bi
        if (lane == j)  { myw = w; myi = bi; }
        if (lane == bi) cur = -INFINITY;
    }

    if (lane < KTOP) {
        out[(size_t)row * KTOP + lane] = myw;
        out[(size_t)T_DIM * KTOP + (size_t)row * KTOP + lane] = (float)myi;
    }
}

extern "C" void kernel_launch(void* const* d_in, const int* in_sizes, int n_in,
                              void* d_out, int out_size, void* d_ws, size_t ws_size,
                              hipStream_t stream)
{
    const float* x  = (const float*)d_in[0];
    const float* Wg = (const float*)d_in[1];
    const float* Wc = (const float*)d_in[2];
    const float* sc = (const float*)d_in[3];
    const float* bs = (const float*)d_in[4];
    float* out = (float*)d_out;
    float* P   = (float*)d_ws;

    const size_t PER = (size_t)T_DIM * N2 * sizeof(float);           // 4 MB per slice
    const size_t WSP = (size_t)N2 * D_DIM * sizeof(unsigned short);  // 1 MB per W part

    // Need S*4MB (partials) + 3MB (packed W); degrade gracefully if ws is small.
    int S = 8;
    while (S > 1 && (size_t)S * PER + 3 * WSP > ws_size) S >>= 1;
    const int sliceK = D_DIM / S;

    unsigned short* Wpk = (unsigned short*)((char*)d_ws + (size_t)S * PER);

    router_prep<<<256, 256, 0, stream>>>(Wg, Wc, Wpk);
    router_gemm<<<dim3(T_DIM / MB_ROWS, S), 256, 0, stream>>>(x, Wpk, P, sliceK);
    router_topk<<<T_DIM / 4, 256, 0, stream>>>(P, sc, bs, out, S);
}

// Round 13
// 245.291 us; speedup vs baseline: 1.0658x; 1.0482x over previous
//
#include <hip/hip_runtime.h>
#include <math.h>

// Router: x[8192,4096] fp32; Wg,Wc[64,4096]; scores=|cls*silu(gate)|, softmax,
// top-8 of scores+bias, weights = 1 + scores*extra_scale (gathered).
// Out: weights [8192,8] fp32, then indices [8192,8] written as float values.
//
// v12 = v8b (best measured, 249us) + two pipeline deltas, math untouched:
//  - all 6 B loads hoisted BEFORE the x-prefetch issue: vmcnt retires in-order
//    (m135), so v8b's MFMA wait-for-B drained the just-issued ~900cy HBM
//    x-loads every step. Now B-wait = vmcnt(2); WRITE's xa (issued one full
//    step earlier) is already retired -> no exposed VMEM waits.
//  - setprio(1/0) around the MFMA cluster (4 independent blocks/CU drift out
//    of barrier phase -> scheduler has something to arbitrate).
// Math/bits identical to v5..v11 (3-way bf16 split, 6-product order, same
// per-acc k-order, S=8) -> P bit-identical -> absmax 0.

#define T_DIM 8192
#define D_DIM 4096
#define E_DIM 64
#define N2    128      // 64 gate cols + 64 cls cols
#define KTOP  8
#define MB_ROWS 64     // rows per workgroup (wave = all 64 rows x 32 cols)

// LDS fragment layout strides (ushorts): [bf][rg][p][h2][le][j]
#define LDS_H2S 512
#define LDS_PS  1040   // 1024 + 16 pad -> parts shifted 8 banks
#define LDS_RGS (3 * LDS_PS)
#define LDS_BFS (2 * LDS_RGS)

typedef __attribute__((ext_vector_type(8)))  short bfrag8;   // 8 bf16 (4 VGPRs)
typedef __attribute__((ext_vector_type(16))) float f32x16;   // 32x32 C/D frag
typedef __attribute__((ext_vector_type(4)))  float f4;       // clang vec (nt ok)

__device__ __forceinline__ unsigned short f2bf_rne(float f) {
    unsigned int u = __float_as_uint(f);
    unsigned int r = u + 0x7fffu + ((u >> 16) & 1u);        // round-nearest-even
    return (unsigned short)(r >> 16);
}
__device__ __forceinline__ float bf2f(unsigned short h) {
    return __uint_as_float(((unsigned int)h) << 16);
}
// v = bf2f(h) + bf2f(m) + bf2f(l) + eps, |eps| <= 2^-27 |v|
__device__ __forceinline__ void split3(float v, unsigned short& h,
                                       unsigned short& m, unsigned short& l) {
    h = f2bf_rne(v);
    const float r1 = v - bf2f(h);          // exact in fp32
    m = f2bf_rne(r1);
    const float r2 = r1 - bf2f(m);         // exact in fp32
    l = f2bf_rne(r2);
}

// ---------------- Kernel 0: W -> packed fragment-major bf16 hi/mid/lo ----------
// Wpk element index: ((((k32*4 + n)*3 + p)*2 + h2)*64 + lane)*8 + j
//   holds part-p of W[col = n*32 + (lane&31)][k32*32 + h2*16 + (lane>>5)*8 + j]
// => a wave's B fragment load is 64 lanes x 16B CONTIGUOUS (1 KB). Total 3 MB.
__global__ __launch_bounds__(256)
void router_prep(const float* __restrict__ Wg, const float* __restrict__ Wc,
                 unsigned short* __restrict__ Wpk)
{
    const int t   = blockIdx.x * 256 + threadIdx.x;  // 65536 threads
    const int col = t >> 9;                          // 0..127
    const int ch  = t & 511;                         // 8-float chunk within row
    const int k   = ch << 3;

    const float* src = (col < E_DIM) ? (Wg + (size_t)col * D_DIM)
                                     : (Wc + (size_t)(col - E_DIM) * D_DIM);
    const float4 w0 = ((const float4*)(src + k))[0];
    const float4 w1 = ((const float4*)(src + k))[1];
    const float v[8] = {w0.x, w0.y, w0.z, w0.w, w1.x, w1.y, w1.z, w1.w};

    unsigned short hv[8], mv[8], lv[8];
    #pragma unroll
    for (int j = 0; j < 8; ++j) split3(v[j], hv[j], mv[j], lv[j]);

    const int k32 = k >> 5, h2 = (k >> 4) & 1, lh = (k >> 3) & 1;
    const int n = col >> 5, lane = lh * 32 + (col & 31);
    const size_t base = ((((size_t)k32 * 4 + n) * 3 + 0) * 2 + h2) * 512 + (size_t)lane * 8;
    // p stride = 2*512 = 1024 elements
    *(ushort4*)(Wpk + base)          = make_ushort4(hv[0], hv[1], hv[2], hv[3]);
    *(ushort4*)(Wpk + base + 4)      = make_ushort4(hv[4], hv[5], hv[6], hv[7]);
    *(ushort4*)(Wpk + base + 1024)   = make_ushort4(mv[0], mv[1], mv[2], mv[3]);
    *(ushort4*)(Wpk + base + 1028)   = make_ushort4(mv[4], mv[5], mv[6], mv[7]);
    *(ushort4*)(Wpk + base + 2048)   = make_ushort4(lv[0], lv[1], lv[2], lv[3]);
    *(ushort4*)(Wpk + base + 2052)   = make_ushort4(lv[4], lv[5], lv[6], lv[7]);
}

// ---------------- Kernel 1: 3-way-split MFMA GEMM, partials P[ks][T][128] ------
// Block: 256 thr = 4 waves; wave wc owns cols wc*32..wc*32+31 and ALL 64 rows
// (two 32-row groups -> acc[2]). Staging thread (srow=tid>>3, kq=tid&7) loads
// rows srow and srow+32 (nt f4), split3 once, ds_writes fragment layout.
__global__ __launch_bounds__(256, 4)
void router_gemm(const float* __restrict__ x,
                 const unsigned short* __restrict__ Wpk,
                 float* __restrict__ P,
                 int sliceK)
{
    __shared__ unsigned short sF[2 * LDS_BFS];       // ~25 KB

    const int tid  = threadIdx.x;
    const int lane = tid & 63;
    const int wc   = tid >> 6;           // wave = col-quarter (B n-tile)
    const int l31  = lane & 31;
    const int lh   = lane >> 5;
    const int mb   = blockIdx.x;
    const int ks   = blockIdx.y;
    const int k0   = ks * sliceK;
    const int NT   = sliceK >> 5;        // 32-k steps
    const int brow0 = mb * MB_ROWS;

    // staging map: thread -> (srow, kq); covers rows srow and srow+32
    const int srow = tid >> 3;           // 0..31
    const int kq   = tid & 7;            // float4 chunk within 32-k step
    const int h2w  = kq >> 2;
    const int lew  = ((kq >> 1) & 1) * 32 + srow;
    const int jw   = (kq & 1) * 4;
    const int wbase = h2w * LDS_H2S + lew * 8 + jw;  // + bf*BFS + rg*RGS + p*PS
    const float* gsrc0 = x + (size_t)(brow0 + srow) * D_DIM + k0 + kq * 4;
    const float* gsrc1 = gsrc0 + (size_t)32 * D_DIM;

    f32x16 acc[2];
    #pragma unroll
    for (int rg = 0; rg < 2; ++rg)
        #pragma unroll
        for (int r = 0; r < 16; ++r) acc[rg][r] = 0.f;

    // split one f4 into LDS at (bf, rg)
    #define WRITE_HALF(v_, bf_, rg_)                                             \
        {                                                                        \
            ushort4 hv_, mv_, lv_;                                               \
            unsigned short h_, m_, l_;                                           \
            split3((v_).x, h_, m_, l_); hv_.x = h_; mv_.x = m_; lv_.x = l_;      \
            split3((v_).y, h_, m_, l_); hv_.y = h_; mv_.y = m_; lv_.y = l_;      \
            split3((v_).z, h_, m_, l_); hv_.z = h_; mv_.z = m_; lv_.z = l_;      \
            split3((v_).w, h_, m_, l_); hv_.w = h_; mv_.w = m_; lv_.w = l_;      \
            const int o_ = (bf_) * LDS_BFS + (rg_) * LDS_RGS + wbase;            \
            *(ushort4*)&sF[o_]              = hv_;                               \
            *(ushort4*)&sF[o_ + LDS_PS]     = mv_;                               \
            *(ushort4*)&sF[o_ + 2 * LDS_PS] = lv_;                               \
        }

    // prologue: stage tile 0, start prefetch of tile 1
    {
        const f4 v0 = __builtin_nontemporal_load((const f4*)gsrc0);
        const f4 v1 = __builtin_nontemporal_load((const f4*)gsrc1);
        WRITE_HALF(v0, 0, 0);
        WRITE_HALF(v1, 0, 1);
    }
    f4 xa0 = {0,0,0,0}, xa1 = {0,0,0,0};   // data for tile t+1
    f4 xb0 = {0,0,0,0}, xb1 = {0,0,0,0};   // data for tile t+2
    if (NT > 1) {
        xa0 = __builtin_nontemporal_load((const f4*)(gsrc0 + 32));
        xa1 = __builtin_nontemporal_load((const f4*)(gsrc1 + 32));
    }
    asm volatile("s_waitcnt lgkmcnt(0)" ::: "memory");
    __builtin_amdgcn_s_barrier();

    for (int t = 0; t < NT; ++t) {
        const int bf = t & 1;
        const size_t k32 = (size_t)((k0 + t * 32) >> 5);

        // ---- B loads FIRST (L2-hot): MFMA's B-wait = vmcnt(2), never drains
        //      the HBM x-prefetch issued below (in-order retirement, m135).
        const unsigned short* bb =
            Wpk + (((k32 * 4 + wc) * 3) * 2 * 64 + (size_t)lane) * 8;
        const bfrag8 bh0 = *(const bfrag8*)(bb);
        const bfrag8 bm0 = *(const bfrag8*)(bb + 1024);
        const bfrag8 bl0 = *(const bfrag8*)(bb + 2048);
        const bfrag8 bh1 = *(const bfrag8*)(bb + 512);
        const bfrag8 bm1 = *(const bfrag8*)(bb + 1536);
        const bfrag8 bl1 = *(const bfrag8*)(bb + 2560);

        // ---- x prefetch LAST (youngest; depth-2 -> consumed next step)
        if (t + 2 < NT) {
            xb0 = __builtin_nontemporal_load((const f4*)(gsrc0 + (t + 2) * 32));
            xb1 = __builtin_nontemporal_load((const f4*)(gsrc1 + (t + 2) * 32));
        }

        // ---- A frags (linear conflict-free ds_read_b128) + MFMAs; per-acc
        //      order identical to v3..v11 (h2=0 six, then h2=1 six).
        __builtin_amdgcn_s_setprio(1);
        #pragma unroll
        for (int rg = 0; rg < 2; ++rg) {
            const int ab = bf * LDS_BFS + rg * LDS_RGS + lane * 8;
            const bfrag8 ah0 = *(const bfrag8*)&sF[ab];
            const bfrag8 am0 = *(const bfrag8*)&sF[ab + LDS_PS];
            const bfrag8 al0 = *(const bfrag8*)&sF[ab + 2 * LDS_PS];
            const bfrag8 ah1 = *(const bfrag8*)&sF[ab + LDS_H2S];
            const bfrag8 am1 = *(const bfrag8*)&sF[ab + LDS_H2S + LDS_PS];
            const bfrag8 al1 = *(const bfrag8*)&sF[ab + LDS_H2S + 2 * LDS_PS];
            // h2 = 0, smallest products first
            acc[rg] = __builtin_amdgcn_mfma_f32_32x32x16_bf16(ah0, bl0, acc[rg], 0, 0, 0);
            acc[rg] = __builtin_amdgcn_mfma_f32_32x32x16_bf16(al0, bh0, acc[rg], 0, 0, 0);
            acc[rg] = __builtin_amdgcn_mfma_f32_32x32x16_bf16(am0, bm0, acc[rg], 0, 0, 0);
            acc[rg] = __builtin_amdgcn_mfma_f32_32x32x16_bf16(ah0, bm0, acc[rg], 0, 0, 0);
            acc[rg] = __builtin_amdgcn_mfma_f32_32x32x16_bf16(am0, bh0, acc[rg], 0, 0, 0);
            acc[rg] = __builtin_amdgcn_mfma_f32_32x32x16_bf16(ah0, bh0, acc[rg], 0, 0, 0);
            // h2 = 1
            acc[rg] = __builtin_amdgcn_mfma_f32_32x32x16_bf16(ah1, bl1, acc[rg], 0, 0, 0);
            acc[rg] = __builtin_amdgcn_mfma_f32_32x32x16_bf16(al1, bh1, acc[rg], 0, 0, 0);
            acc[rg] = __builtin_amdgcn_mfma_f32_32x32x16_bf16(am1, bm1, acc[rg], 0, 0, 0);
            acc[rg] = __builtin_amdgcn_mfma_f32_32x32x16_bf16(ah1, bm1, acc[rg], 0, 0, 0);
            acc[rg] = __builtin_amdgcn_mfma_f32_32x32x16_bf16(am1, bh1, acc[rg], 0, 0, 0);
            acc[rg] = __builtin_amdgcn_mfma_f32_32x32x16_bf16(ah1, bh1, acc[rg], 0, 0, 0);
        }
        __builtin_amdgcn_s_setprio(0);

        // ---- write tile t+1 (xa issued a full step ago -> already retired)
        if (t + 1 < NT) {
            WRITE_HALF(xa0, bf ^ 1, 0);
            WRITE_HALF(xa1, bf ^ 1, 1);
        }
        // barrier: LDS visibility only -- x prefetch stays in flight
        asm volatile("s_waitcnt lgkmcnt(0)" ::: "memory");
        __builtin_amdgcn_s_barrier();
        xa0 = xb0; xa1 = xb1;
    }
    #undef WRITE_HALF

    // store partial C tile: P[ks][row][col], non-temporal (read once by topk)
    // C/D (m74/m101): col = lane&31, row = (r&3) + 8*(r>>2) + 4*(lane>>5)
    #pragma unroll
    for (int rg = 0; rg < 2; ++rg) {
        float* Pb = P + ((size_t)ks * T_DIM + brow0 + rg * 32) * N2 + wc * 32 + l31;
        #pragma unroll
        for (int r = 0; r < 16; ++r) {
            const int wrow = (r & 3) + 8 * (r >> 2) + 4 * lh;
            __builtin_nontemporal_store(acc[rg][r], &Pb[(size_t)wrow * N2]);
        }
    }
}

// ---------------- Kernel 2: reduce slices + silu/abs/softmax + biased top-8 ----
// (unchanged from the passing kernel — exact index ordering proven)
__global__ __launch_bounds__(256)
void router_topk(const float* __restrict__ P,
                 const float* __restrict__ scale,
                 const float* __restrict__ bias,
                 float* __restrict__ out,
                 int ksplit)
{
    const int lane = threadIdx.x & 63;   // expert id
    const int wid  = threadIdx.x >> 6;
    const int row  = blockIdx.x * 4 + wid;

    float g = 0.f, c = 0.f;
    for (int ks = 0; ks < ksplit; ++ks) {
        const float* p = P + ((size_t)ks * T_DIM + row) * N2;
        g += p[lane];
        c += p[E_DIM + lane];
    }
    const float sg = g / (1.f + expf(-g));   // silu(gate)
    const float v  = fabsf(c * sg);          // score pre-softmax

    // fp32 softmax across the 64 lanes
    float m = v;
    #pragma unroll
    for (int off = 32; off >= 1; off >>= 1) m = fmaxf(m, __shfl_xor(m, off));
    const float e = expf(v - m);
    float Z = e;
    #pragma unroll
    for (int off = 32; off >= 1; off >>= 1) Z += __shfl_xor(Z, off);
    const float s = e / Z;

    const float sc  = scale[lane];
    float cur = s + bias[lane];              // selection key

    float myw = 0.f; int myi = 0;
    #pragma unroll
    for (int j = 0; j < KTOP; ++j) {
        // wave argmax, ties -> lowest index (matches jax.lax.top_k)
        float bv = cur; int bi = lane;
        #pragma unroll
        for (int off = 32; off >= 1; off >>= 1) {
            const float ov = __shfl_xor(bv, off);
            const int   oi = __shfl_xor(bi, off);
            if (ov > bv || (ov == bv && oi < bi)) { bv = ov; bi = oi; }
        }
        const float s_bi  = __shfl(s,  bi);
        const float sc_bi = __shfl(sc, bi);
        const float w = 1.f + s_bi * sc_bi;  // "original" gathered at bi
        if (lane == j)  { myw = w; myi = bi; }
        if (lane == bi) cur = -INFINITY;
    }

    if (lane < KTOP) {
        out[(size_t)row * KTOP + lane] = myw;
        out[(size_t)T_DIM * KTOP + (size_t)row * KTOP + lane] = (float)myi;
    }
}

extern "C" void kernel_launch(void* const* d_in, const int* in_sizes, int n_in,
                              void* d_out, int out_size, void* d_ws, size_t ws_size,
                              hipStream_t stream)
{
    const float* x  = (const float*)d_in[0];
    const float* Wg = (const float*)d_in[1];
    const float* Wc = (const float*)d_in[2];
    const float* sc = (const float*)d_in[3];
    const float* bs = (const float*)d_in[4];
    float* out = (float*)d_out;
    float* P   = (float*)d_ws;

    const size_t PER = (size_t)T_DIM * N2 * sizeof(float);           // 4 MB per slice
    const size_t WSP = (size_t)N2 * D_DIM * sizeof(unsigned short);  // 1 MB per W part

    // Need S*4MB (partials) + 3MB (packed W); degrade gracefully if ws is small.
    int S = 8;
    while (S > 1 && (size_t)S * PER + 3 * WSP > ws_size) S >>= 1;
    const int sliceK = D_DIM / S;

    unsigned short* Wpk = (unsigned short*)((char*)d_ws + (size_t)S * PER);

    router_prep<<<256, 256, 0, stream>>>(Wg, Wc, Wpk);
    router_gemm<<<dim3(T_DIM / MB_ROWS, S), 256, 0, stream>>>(x, Wpk, P, sliceK);
    router_topk<<<T_DIM / 4, 256, 0, stream>>>(P, sc, bs, out, S);
}